// Round 3
// baseline (385.341 us; speedup 1.0000x reference)
//
#include <hip/hip_runtime.h>
#include <math.h>

// BridgeNodes R3: scalar-A outer product. Wave = 8 rows x 64 cols (lane=col).
// A fragments: uniform-address float4 loads -> s_load_dwordx4 (SGPR operand in
// fma, scalar pipe parallel to VALU). B: 32-k chunk held in 32 VGPRs/lane,
// filled per kc by 8 xor-swizzled ds_read_b128 (8-phase minimal). Inner loop
// is pure FMA. Upper-tri tiles + LDS-transpose mirror as in R2.
// Same ascending-k fmaf chain + expf sigmoid => bitwise-identical output.

constexpr int GROUPS = 4;
constexpr int N = 4096;
constexpr int F = 128;
constexpr int BT = 64;                           // tile edge
constexpr int KS = 32;                           // K chunk
constexpr int TILES = N / BT;                    // 64
constexpr int PAIRS = TILES * (TILES + 1) / 2;   // 2080
constexpr int TPAD = 68;                         // transpose buffer row stride (floats)
constexpr float THRESH = 0.6f;

__device__ __forceinline__ int row_start(int r) { return r * TILES - (r * (r - 1)) / 2; }

__global__ __launch_bounds__(512, 8)
void bridge_nodes_kernel(const float* __restrict__ nodes, float* __restrict__ out) {
    __shared__ float Bs[BT * KS];                // 8 KB, xor-swizzled 16B granules
    __shared__ float T[BT * TPAD];               // 17.4 KB mirror transpose buffer

    const int g = blockIdx.y;
    const int t = blockIdx.x;

    // t -> (bm, bn), bm <= bn
    int bm = (int)((2 * TILES + 1
                    - sqrtf((float)((2 * TILES + 1) * (2 * TILES + 1) - 8 * t))) * 0.5f);
    bm = bm < 0 ? 0 : (bm > TILES - 1 ? TILES - 1 : bm);
    while (row_start(bm) > t) --bm;
    while (row_start(bm + 1) <= t) ++bm;
    const int bn = bm + (t - row_start(bm));

    const float* __restrict__ base = nodes + (size_t)g * N * F;
    const int tid  = threadIdx.x;
    const int lane = tid & 63;                   // = my column within the tile
    // wave row base: force wave-uniform so A loads scalarize to s_load
    const int wrow = __builtin_amdgcn_readfirstlane((tid >> 6) * 8);
    const float* __restrict__ Arow = base + (size_t)(bm * BT + wrow) * F;

    // staging ids: thread t loads (row srow, k-quad skq) of the B tile
    const int srow = tid >> 3;                   // 0..63
    const int skq  = tid & 7;                    // 0..7
    const float* __restrict__ Bld = base + (size_t)(bn * BT + srow) * F + skq * 4;
    float4* BsG = (float4*)Bs;
    const int wgran = srow * 8 + (skq ^ (srow & 7));   // swizzled granule index

    float acc[8] = {0.f, 0.f, 0.f, 0.f, 0.f, 0.f, 0.f, 0.f};

    float4 bv = *(const float4*)(Bld);           // prefetch kc=0
#pragma unroll
    for (int kc = 0; kc < F / KS; ++kc) {
        const int kb = kc * KS;
        __syncthreads();                         // prior kc's reads done
        BsG[wgran] = bv;
        __syncthreads();
        if (kc < F / KS - 1)
            bv = *(const float4*)(Bld + (kb + KS));    // prefetch next kc

        // fill B regs for my column: granule q holds k = kb + 4q .. +3
        float4 breg[8];
#pragma unroll
        for (int q = 0; q < 8; ++q)
            breg[q] = BsG[lane * 8 + (q ^ (lane & 7))];

        // A quads (uniform -> SGPR) + pure-FMA inner loop, ascending k
#pragma unroll
        for (int q = 0; q < 8; ++q) {
            float4 a[8];
#pragma unroll
            for (int r = 0; r < 8; ++r)
                a[r] = *(const float4*)(Arow + r * F + kb + q * 4);
            const float4 b = breg[q];
            // k ascending: component c outer, rows inner (chain per acc[r] is
            // ascending-k fmaf, bitwise == R1/R2)
#pragma unroll
            for (int r = 0; r < 8; ++r) acc[r] = fmaf(a[r].x, b.x, acc[r]);
#pragma unroll
            for (int r = 0; r < 8; ++r) acc[r] = fmaf(a[r].y, b.y, acc[r]);
#pragma unroll
            for (int r = 0; r < 8; ++r) acc[r] = fmaf(a[r].z, b.z, acc[r]);
#pragma unroll
            for (int r = 0; r < 8; ++r) acc[r] = fmaf(a[r].w, b.w, acc[r]);
        }
    }

    // sigmoid + threshold (precise expf, same as R1/R2)
#pragma unroll
    for (int r = 0; r < 8; ++r) {
        const float s = 1.0f / (1.0f + expf(-acc[r]));
        acc[r] = (s < THRESH) ? 0.0f : s;
    }

    // direct store of tile (bm, bn): 64 lanes dense per row
    const size_t outg = (size_t)g * N * N;
    {
        float* o = out + outg + (size_t)(bm * BT + wrow) * N + bn * BT + lane;
#pragma unroll
        for (int r = 0; r < 8; ++r) o[(size_t)r * N] = acc[r];
    }

    // mirror store of tile (bn, bm) via LDS transpose
    if (bm != bn) {
        // lane writes its 8 values (rows wrow..wrow+7 of col `lane`) contiguously
        float4 t0 = {acc[0], acc[1], acc[2], acc[3]};
        float4 t1 = {acc[4], acc[5], acc[6], acc[7]};
        *(float4*)&T[lane * TPAD + wrow]     = t0;
        *(float4*)&T[lane * TPAD + wrow + 4] = t1;
        __syncthreads();
        // thread reads mirror row mr = tid>>3, 8 cols starting at (tid&7)*8
        const int mr = tid >> 3;
        const int qc = (tid & 7) * 8;
        const float4 v0 = *(const float4*)&T[mr * TPAD + qc];
        const float4 v1 = *(const float4*)&T[mr * TPAD + qc + 4];
        float* o = out + outg + (size_t)(bn * BT + mr) * N + bm * BT + qc;
        *(float4*)o = v0;
        *(float4*)(o + 4) = v1;
    }
}

extern "C" void kernel_launch(void* const* d_in, const int* in_sizes, int n_in,
                              void* d_out, int out_size, void* d_ws, size_t ws_size,
                              hipStream_t stream) {
    const float* nodes = (const float*)d_in[0];
    float* out = (float*)d_out;
    dim3 grid(PAIRS, GROUPS);                    // 2080 x 4 = 8320 blocks
    dim3 block(512);
    bridge_nodes_kernel<<<grid, block, 0, stream>>>(nodes, out);
}